// Round 10
// baseline (231.294 us; speedup 1.0000x reference)
//
#include <hip/hip_runtime.h>
#include <hip/hip_fp16.h>

namespace {
constexpr int Bn = 2, Cin = 64, Cout = 64;
constexpr int Dd = 8, Hh = 48, Wd = 48;
constexpr int K = 27;
constexpr int SP = Dd * Hh * Wd;   // 18432
constexpr int PLANE = Hh * Wd;     // 2304
constexpr int NTILE = SP / 64;     // 288 position tiles per batch
constexpr int KC = 3;              // K-split factor (main GEMM); KPER = 9
constexpr int KPER = K / KC;
constexpr int CS = 2;              // cin-split factor (offset conv)
}

typedef __attribute__((ext_vector_type(8))) _Float16 half8;
typedef __attribute__((ext_vector_type(4))) float f32x4;

__device__ __forceinline__ unsigned short f2h(float f) {  // RNE float->f16 bits
  return __half_as_ushort(__float2half(f));
}
__device__ __forceinline__ __half2 u2h2(unsigned u) {
  return __builtin_bit_cast(__half2, u);
}
__device__ __forceinline__ unsigned h22u(__half2 h) {
  return __builtin_bit_cast(unsigned, h);
}

// x [B,C,D,H,W] -> xTh [B, spatial, C] f16 (channels-last)
__global__ __launch_bounds__(256) void k_xTh(const float* __restrict__ x,
                                             unsigned short* __restrict__ xTh) {
  int i = blockIdx.x * 256 + threadIdx.x;   // B*SP*Cin = 2,359,296
  int c = i & 63;
  int rest = i >> 6;
  int p = rest % SP;
  int b = rest / SP;
  xTh[i] = f2h(x[(b * Cin + c) * SP + p]);
}

// main weights -> per-lane-contiguous MFMA A-frag layout, f16:
// wTb[k][mt(4)][s(2)][row(16)][kg(4)][j(8)] ; co = mt*16+row, cin = s*32+kg*8+j
__global__ __launch_bounds__(256) void k_wTb(const float* __restrict__ w,
                                             unsigned short* __restrict__ wTb) {
  int i = blockIdx.x * 256 + threadIdx.x;   // 27*4096 = 110,592
  int j = i & 7, kg = (i >> 3) & 3, row = (i >> 5) & 15;
  int s = (i >> 9) & 1, mt = (i >> 10) & 3, k = i >> 12;
  int co = mt * 16 + row, cin = s * 32 + kg * 8 + j;
  wTb[i] = f2h(w[((size_t)co * Cin + cin) * K + k]);
}

// offset-conv weights -> A-frag layout keyed by (tap, cin-half):
// wq[tap][cs(2)][mt(6)][row(16)][kg(4)][j(8)] ; ch = mt*16+row (pad >=81 -> 0),
// cin = cs*32+kg*8+j
__global__ __launch_bounds__(256) void k_offwq(const float* __restrict__ cw,
                                               unsigned short* __restrict__ wq) {
  int i = blockIdx.x * 256 + threadIdx.x;   // 27*2*6*512 = 165,888
  int j = i & 7, kg = (i >> 3) & 3, row = (i >> 5) & 15;
  int rest = i >> 9;          // 0..323
  int mt = rest % 6;
  int rest2 = rest / 6;       // 0..53
  int cs = rest2 & 1;
  int tap = rest2 >> 1;
  int ch = mt * 16 + row, cin = cs * 32 + kg * 8 + j;
  float v = (ch < 81) ? cw[((size_t)ch * 64 + cin) * 27 + tap] : 0.f;
  wq[i] = f2h(v);
}

// Offset conv, barrier-free MFMA (validated round 9). No LDS.
__global__ __launch_bounds__(256) void k_offm3(const unsigned short* __restrict__ xTh,
                                               const unsigned short* __restrict__ wq,
                                               float* __restrict__ opart) {
  const int t = threadIdx.x;
  const int lane = t & 63;
  const int wv = t >> 6;
  const int bid = blockIdx.x;              // cs*576 + nb ; 1152 total
  const int cs = bid / 576;
  const int nb = bid - cs * 576;
  const int n0 = nb * 64;
  const int b = n0 / SP;
  const int sp0 = n0 - b * SP;

  const int q = sp0 + wv * 16 + (lane & 15);   // this lane's output position
  const int d = q / PLANE;
  const int rp = q - d * PLANE;
  const int h = rp / 48;
  const int w = rp - h * 48;

  const unsigned short* xb =
      xTh + ((size_t)b * SP + q) * 64 + cs * 32 + (lane >> 4) * 8;
  const unsigned short* wbase =
      wq + cs * 3072 + (lane & 15) * 32 + (lane >> 4) * 8;

  f32x4 acc[6];
#pragma unroll
  for (int mt = 0; mt < 6; ++mt) acc[mt] = f32x4{0.f, 0.f, 0.f, 0.f};

#pragma unroll
  for (int tap = 0; tap < 27; ++tap) {
    const int kd = tap / 9, kh = (tap % 9) / 3, kw = tap % 3;
    const int dd = d + kd - 1, hh = h + kh - 1, ww = w + kw - 1;
    const bool valid = ((unsigned)dd < 8u) & ((unsigned)hh < 48u) & ((unsigned)ww < 48u);
    const int delta = ((kd - 1) * PLANE + (kh - 1) * 48 + (kw - 1)) * 64;
    half8 bf = {};
    if (valid) bf = *reinterpret_cast<const half8*>(xb + delta);
    const unsigned short* wt = wbase + tap * 6144;
#pragma unroll
    for (int mt = 0; mt < 6; ++mt) {
      half8 af = *reinterpret_cast<const half8*>(wt + mt * 512);
      acc[mt] = __builtin_amdgcn_mfma_f32_16x16x32_f16(af, bf, acc[mt], 0, 0, 0);
    }
  }

  // opart[cs][b][ch][colp], ch<81
  const int colp = sp0 + wv * 16 + (lane & 15);
  float* pp = opart + (size_t)(cs * 2 + b) * 81 * SP;
#pragma unroll
  for (int mt = 0; mt < 6; ++mt) {
#pragma unroll
    for (int reg = 0; reg < 4; ++reg) {
      int ch = mt * 16 + (lane >> 4) * 4 + reg;
      if (ch < 81)
        pp[(size_t)ch * SP + colp] = acc[mt][reg];
    }
  }
}

// off[b][ch][p] = cb[ch] + sum_cs opart[cs][b][ch][p]  (float4)
__global__ __launch_bounds__(256) void k_offred(const float* __restrict__ opart,
                                                const float* __restrict__ cb,
                                                float* __restrict__ off) {
  int i = blockIdx.x * 256 + threadIdx.x;  // 2*81*SP/4 = 746,496
  int p4 = i % (SP / 4);
  int ch = (i / (SP / 4)) % 81;
  int b = i / ((SP / 4) * 81);
  size_t base = ((size_t)b * 81 + ch) * SP + p4 * 4;
  float4 s = *reinterpret_cast<const float4*>(&opart[base]);
#pragma unroll
  for (int cs = 1; cs < CS; ++cs) {
    float4 v = *reinterpret_cast<const float4*>(&opart[base + (size_t)cs * 2 * 81 * SP]);
    s.x += v.x; s.y += v.y; s.z += v.z; s.w += v.w;
  }
  float bb = cb[ch];
  s.x += bb; s.y += bb; s.z += bb; s.w += bb;
  *reinterpret_cast<float4*>(&off[base]) = s;
}

// Fused gather + MFMA GEMM, barrier-free. Block tile: 64 pos x 64 co, K-split
// across blocks, XCD-aware tile swizzle. Lane (wv,l) gathers position
// wv*16+(l&15), channel chunk s*4+(l>>4): the blended half2[4] IS the MFMA
// B-fragment -> no vals LDS, no __syncthreads anywhere. Corner metadata is
// exchanged wave-locally through a per-wave scp row (same-wave LDS ordering).
__global__ __launch_bounds__(256) void k_mainp(const unsigned short* __restrict__ xTh,
                                               const float* __restrict__ off,
                                               const unsigned short* __restrict__ wTb,
                                               float* __restrict__ part) {
  __shared__ __align__(16) unsigned scp[4 * 16 * 20];  // [wave][pos(16)][20 words]

  const int t = threadIdx.x;
  const int lane = t & 63;
  const int wv = t >> 6;
  const int bid = blockIdx.x;                    // kc*576 + j
  const int kc = bid / 576;
  const int j = bid - kc * 576;
  const int tl = (j & 7) * 72 + (j >> 3);        // XCD-contiguous tile blocks
  const int b = tl / NTILE;
  const int tile = tl - b * NTILE;
  const int p0 = tile * 64;

  const char* xb8 = (const char*)(xTh + (size_t)b * SP * 64);
  const float* offb = off + (size_t)b * 81 * SP;

  const int posl = lane & 15;
  const int quad = lane >> 4;
  const int p = p0 + wv * 16 + posl;             // this lane's position
  const int d = p / PLANE;
  const int rp = p - d * PLANE;
  const int h = rp / 48;
  const int w = rp - h * 48;
  const int kd = kc;                              // KPER==9 -> k/9 == kc

  unsigned* myrow = &scp[(wv * 16 + posl) * 20];
  const unsigned short* wkl = wTb + posl * 32 + quad * 8;  // + k*4096 + mt*1024 + s*512

  f32x4 acc[4];
#pragma unroll
  for (int mt = 0; mt < 4; ++mt) acc[mt] = f32x4{0.f, 0.f, 0.f, 0.f};

#pragma unroll
  for (int kk = 0; kk < KPER; ++kk) {
    const int k = kc * KPER + kk;
    const int kh = kk / 3, kw2 = kk % 3;
    // ---- setup: this lane computes corners quad*2, quad*2+1 of position p
    {
      float pd = (float)(d + kd - 1) + offb[k * SP + p];
      float ph = (float)(h + kh - 1) + offb[(27 + k) * SP + p];
      float pw = (float)(w + kw2 - 1) + offb[(54 + k) * SP + p];
      float df = floorf(pd), hf = floorf(ph), wf = floorf(pw);
      float fd = pd - df, fh = ph - hf, fw = pw - wf;
      int d0 = (int)df, h0 = (int)hf, w0i = (int)wf;
      unsigned pk[4];
#pragma unroll
      for (int cc = 0; cc < 2; ++cc) {
        int c = quad * 2 + cc;
        int cd = c >> 2, ch = (c >> 1) & 1, cwb = c & 1;
        int di = d0 + cd, hi = h0 + ch, wi = w0i + cwb;
        bool v = ((unsigned)di < 8u) && ((unsigned)hi < 48u) && ((unsigned)wi < 48u);
        float wg = (cd ? fd : 1.f - fd) * (ch ? fh : 1.f - fh) * (cwb ? fw : 1.f - fw);
        int dic = min(max(di, 0), 7), hic = min(max(hi, 0), 47), wic = min(max(wi, 0), 47);
        unsigned hs = (unsigned)f2h(v ? wg : 0.f);
        pk[cc * 2] = (unsigned)((dic * 48 + hic) * 48 + wic);
        pk[cc * 2 + 1] = hs | (hs << 16);
      }
      *reinterpret_cast<uint4*>(myrow + quad * 4) = uint4{pk[0], pk[1], pk[2], pk[3]};
    }
    __builtin_amdgcn_wave_barrier();   // compiler-order fence (same-wave LDS is in-order)
    const uint4 m0 = *reinterpret_cast<const uint4*>(myrow + 0);
    const uint4 m1 = *reinterpret_cast<const uint4*>(myrow + 4);
    const uint4 m2 = *reinterpret_cast<const uint4*>(myrow + 8);
    const uint4 m3 = *reinterpret_cast<const uint4*>(myrow + 12);
    __builtin_amdgcn_wave_barrier();

    const unsigned short* wk = wkl + (size_t)k * 4096;
#pragma unroll
    for (int s = 0; s < 2; ++s) {
      const int cof = (s * 4 + quad) << 4;   // byte offset of this lane's 8-ch chunk
      uint4 q0 = *reinterpret_cast<const uint4*>(xb8 + (((size_t)m0.x << 7) + cof));
      uint4 q1 = *reinterpret_cast<const uint4*>(xb8 + (((size_t)m0.z << 7) + cof));
      uint4 q2 = *reinterpret_cast<const uint4*>(xb8 + (((size_t)m1.x << 7) + cof));
      uint4 q3 = *reinterpret_cast<const uint4*>(xb8 + (((size_t)m1.z << 7) + cof));
      uint4 q4 = *reinterpret_cast<const uint4*>(xb8 + (((size_t)m2.x << 7) + cof));
      uint4 q5 = *reinterpret_cast<const uint4*>(xb8 + (((size_t)m2.z << 7) + cof));
      uint4 q6 = *reinterpret_cast<const uint4*>(xb8 + (((size_t)m3.x << 7) + cof));
      uint4 q7 = *reinterpret_cast<const uint4*>(xb8 + (((size_t)m3.z << 7) + cof));
      __half2 a2[4];
#pragma unroll
      for (int e = 0; e < 4; ++e) a2[e] = u2h2(0u);
      __half2 w0 = u2h2(m0.y), w1 = u2h2(m0.w), w2 = u2h2(m1.y), w3 = u2h2(m1.w);
      __half2 w4 = u2h2(m2.y), w5 = u2h2(m2.w), w6 = u2h2(m3.y), w7 = u2h2(m3.w);
      a2[0] = __hfma2(u2h2(q0.x), w0, a2[0]); a2[1] = __hfma2(u2h2(q0.y), w0, a2[1]);
      a2[2] = __hfma2(u2h2(q0.z), w0, a2[2]); a2[3] = __hfma2(u2h2(q0.w), w0, a2[3]);
      a2[0] = __hfma2(u2h2(q1.x), w1, a2[0]); a2[1] = __hfma2(u2h2(q1.y), w1, a2[1]);
      a2[2] = __hfma2(u2h2(q1.z), w1, a2[2]); a2[3] = __hfma2(u2h2(q1.w), w1, a2[3]);
      a2[0] = __hfma2(u2h2(q2.x), w2, a2[0]); a2[1] = __hfma2(u2h2(q2.y), w2, a2[1]);
      a2[2] = __hfma2(u2h2(q2.z), w2, a2[2]); a2[3] = __hfma2(u2h2(q2.w), w2, a2[3]);
      a2[0] = __hfma2(u2h2(q3.x), w3, a2[0]); a2[1] = __hfma2(u2h2(q3.y), w3, a2[1]);
      a2[2] = __hfma2(u2h2(q3.z), w3, a2[2]); a2[3] = __hfma2(u2h2(q3.w), w3, a2[3]);
      a2[0] = __hfma2(u2h2(q4.x), w4, a2[0]); a2[1] = __hfma2(u2h2(q4.y), w4, a2[1]);
      a2[2] = __hfma2(u2h2(q4.z), w4, a2[2]); a2[3] = __hfma2(u2h2(q4.w), w4, a2[3]);
      a2[0] = __hfma2(u2h2(q5.x), w5, a2[0]); a2[1] = __hfma2(u2h2(q5.y), w5, a2[1]);
      a2[2] = __hfma2(u2h2(q5.z), w5, a2[2]); a2[3] = __hfma2(u2h2(q5.w), w5, a2[3]);
      a2[0] = __hfma2(u2h2(q6.x), w6, a2[0]); a2[1] = __hfma2(u2h2(q6.y), w6, a2[1]);
      a2[2] = __hfma2(u2h2(q6.z), w6, a2[2]); a2[3] = __hfma2(u2h2(q6.w), w6, a2[3]);
      a2[0] = __hfma2(u2h2(q7.x), w7, a2[0]); a2[1] = __hfma2(u2h2(q7.y), w7, a2[1]);
      a2[2] = __hfma2(u2h2(q7.z), w7, a2[2]); a2[3] = __hfma2(u2h2(q7.w), w7, a2[3]);
      uint4 bu{h22u(a2[0]), h22u(a2[1]), h22u(a2[2]), h22u(a2[3])};
      half8 bfr = __builtin_bit_cast(half8, bu);
#pragma unroll
      for (int mt = 0; mt < 4; ++mt) {
        half8 afr = *reinterpret_cast<const half8*>(wk + mt * 1024 + s * 512);
        acc[mt] = __builtin_amdgcn_mfma_f32_16x16x32_f16(afr, bfr, acc[mt], 0, 0, 0);
      }
    }
  }

  // part[kc][b][tile][co][pos]; co = mt*16+quad*4+reg, pos = wv*16+posl
  float* pp = part + ((size_t)(kc * 2 + b) * NTILE + tile) * 4096;
#pragma unroll
  for (int mt = 0; mt < 4; ++mt) {
#pragma unroll
    for (int reg = 0; reg < 4; ++reg) {
      int co = mt * 16 + quad * 4 + reg;
      pp[co * 64 + wv * 16 + posl] = acc[mt][reg];
    }
  }
}

// out[b][co][p] = bias[co] + sum_kc part[kc][b][tile][co][pos]  (float4)
__global__ __launch_bounds__(256) void k_red(const float* __restrict__ part,
                                             const float* __restrict__ bias,
                                             float* __restrict__ out) {
  int i = blockIdx.x * 256 + threadIdx.x;  // 589,824 float4 units
  int p4 = i % (SP / 4);
  int co = (i / (SP / 4)) & 63;
  int b = i / ((SP / 4) * 64);
  int p = p4 * 4;
  int tile = p >> 6, pos = p & 63;
  size_t base = ((size_t)b * NTILE + tile) * 4096 + co * 64 + pos;
  float4 s = *reinterpret_cast<const float4*>(&part[base]);
#pragma unroll
  for (int kc = 1; kc < KC; ++kc) {
    float4 v = *reinterpret_cast<const float4*>(&part[base + (size_t)kc * (2 * NTILE * 4096)]);
    s.x += v.x; s.y += v.y; s.z += v.z; s.w += v.w;
  }
  float bb = bias[co];
  s.x += bb; s.y += bb; s.z += bb; s.w += bb;
  *reinterpret_cast<float4*>(&out[((size_t)(b * 64 + co)) * SP + p]) = s;
}

extern "C" void kernel_launch(void* const* d_in, const int* in_sizes, int n_in,
                              void* d_out, int out_size, void* d_ws, size_t ws_size,
                              hipStream_t stream) {
  const float* x = (const float*)d_in[0];
  const float* cw = (const float*)d_in[1];
  const float* cb = (const float*)d_in[2];
  const float* w = (const float*)d_in[3];
  const float* bias = (const float*)d_in[4];
  float* out = (float*)d_out;

  char* ws = (char*)d_ws;
  float* off = (float*)ws;                                   // 11,943,936 B
  unsigned short* xTh = (unsigned short*)(ws + 11943936);    //  4,718,592 B
  unsigned short* wTb = (unsigned short*)(ws + 16662528);    //    221,184 B
  unsigned short* wq = (unsigned short*)(ws + 16883712);     //    331,776 B
  float* part = (float*)(ws + 17215488);                     // KC*9,437,184 = 28,311,552 B
  float* opart = (float*)(ws + 45527040);                    // CS*11,943,936 = 23,887,872 B

  hipLaunchKernelGGL(k_xTh, dim3(9216), dim3(256), 0, stream, x, xTh);
  hipLaunchKernelGGL(k_wTb, dim3(432), dim3(256), 0, stream, w, wTb);
  hipLaunchKernelGGL(k_offwq, dim3(648), dim3(256), 0, stream, cw, wq);
  hipLaunchKernelGGL(k_offm3, dim3(CS * 576), dim3(256), 0, stream, xTh, wq, opart);
  hipLaunchKernelGGL(k_offred, dim3(2916), dim3(256), 0, stream, opart, cb, off);
  hipLaunchKernelGGL(k_mainp, dim3(KC * 576), dim3(256), 0, stream, xTh, off, wTb, part);
  hipLaunchKernelGGL(k_red, dim3(2304), dim3(256), 0, stream, part, bias, out);
}

// Round 11
// 162.539 us; speedup vs baseline: 1.4230x; 1.4230x over previous
//
#include <hip/hip_runtime.h>
#include <hip/hip_fp16.h>

namespace {
constexpr int Bn = 2, Cin = 64, Cout = 64;
constexpr int Dd = 8, Hh = 48, Wd = 48;
constexpr int K = 27;
constexpr int SP = Dd * Hh * Wd;   // 18432
constexpr int PLANE = Hh * Wd;     // 2304
constexpr int NTILE = SP / 64;     // 288 position tiles per batch
constexpr int KC = 3;              // K-split factor (main GEMM); KPER = 9
constexpr int KPER = K / KC;
constexpr int CS = 2;              // cin-split factor (offset conv)
}

typedef __attribute__((ext_vector_type(8))) _Float16 half8;
typedef __attribute__((ext_vector_type(4))) float f32x4;

__device__ __forceinline__ unsigned short f2h(float f) {  // RNE float->f16 bits
  return __half_as_ushort(__float2half(f));
}
__device__ __forceinline__ __half2 u2h2(unsigned u) {
  return __builtin_bit_cast(__half2, u);
}
__device__ __forceinline__ unsigned h22u(__half2 h) {
  return __builtin_bit_cast(unsigned, h);
}

// x [B,C,D,H,W] -> xTh [B, spatial, C] f16 (channels-last)
__global__ __launch_bounds__(256) void k_xTh(const float* __restrict__ x,
                                             unsigned short* __restrict__ xTh) {
  int i = blockIdx.x * 256 + threadIdx.x;   // B*SP*Cin = 2,359,296
  int c = i & 63;
  int rest = i >> 6;
  int p = rest % SP;
  int b = rest / SP;
  xTh[i] = f2h(x[(b * Cin + c) * SP + p]);
}

// main weights -> per-lane-contiguous MFMA A-frag layout, f16:
// wTb[k][mt(4)][s(2)][row(16)][kg(4)][j(8)] ; co = mt*16+row, cin = s*32+kg*8+j
__global__ __launch_bounds__(256) void k_wTb(const float* __restrict__ w,
                                             unsigned short* __restrict__ wTb) {
  int i = blockIdx.x * 256 + threadIdx.x;   // 27*4096 = 110,592
  int j = i & 7, kg = (i >> 3) & 3, row = (i >> 5) & 15;
  int s = (i >> 9) & 1, mt = (i >> 10) & 3, k = i >> 12;
  int co = mt * 16 + row, cin = s * 32 + kg * 8 + j;
  wTb[i] = f2h(w[((size_t)co * Cin + cin) * K + k]);
}

// offset-conv weights -> A-frag layout keyed by (tap, cin-half):
// wq[tap][cs(2)][mt(6)][row(16)][kg(4)][j(8)] ; ch = mt*16+row (pad >=81 -> 0),
// cin = cs*32+kg*8+j
__global__ __launch_bounds__(256) void k_offwq(const float* __restrict__ cw,
                                               unsigned short* __restrict__ wq) {
  int i = blockIdx.x * 256 + threadIdx.x;   // 27*2*6*512 = 165,888
  int j = i & 7, kg = (i >> 3) & 3, row = (i >> 5) & 15;
  int rest = i >> 9;          // 0..323
  int mt = rest % 6;
  int rest2 = rest / 6;       // 0..53
  int cs = rest2 & 1;
  int tap = rest2 >> 1;
  int ch = mt * 16 + row, cin = cs * 32 + kg * 8 + j;
  float v = (ch < 81) ? cw[((size_t)ch * 64 + cin) * 27 + tap] : 0.f;
  wq[i] = f2h(v);
}

// Offset conv, barrier-free MFMA (validated round 9). No LDS.
__global__ __launch_bounds__(256) void k_offm3(const unsigned short* __restrict__ xTh,
                                               const unsigned short* __restrict__ wq,
                                               float* __restrict__ opart) {
  const int t = threadIdx.x;
  const int lane = t & 63;
  const int wv = t >> 6;
  const int bid = blockIdx.x;              // cs*576 + nb ; 1152 total
  const int cs = bid / 576;
  const int nb = bid - cs * 576;
  const int n0 = nb * 64;
  const int b = n0 / SP;
  const int sp0 = n0 - b * SP;

  const int q = sp0 + wv * 16 + (lane & 15);   // this lane's output position
  const int d = q / PLANE;
  const int rp = q - d * PLANE;
  const int h = rp / 48;
  const int w = rp - h * 48;

  const unsigned short* xb =
      xTh + ((size_t)b * SP + q) * 64 + cs * 32 + (lane >> 4) * 8;
  const unsigned short* wbase =
      wq + cs * 3072 + (lane & 15) * 32 + (lane >> 4) * 8;

  f32x4 acc[6];
#pragma unroll
  for (int mt = 0; mt < 6; ++mt) acc[mt] = f32x4{0.f, 0.f, 0.f, 0.f};

#pragma unroll
  for (int tap = 0; tap < 27; ++tap) {
    const int kd = tap / 9, kh = (tap % 9) / 3, kw = tap % 3;
    const int dd = d + kd - 1, hh = h + kh - 1, ww = w + kw - 1;
    const bool valid = ((unsigned)dd < 8u) & ((unsigned)hh < 48u) & ((unsigned)ww < 48u);
    const int delta = ((kd - 1) * PLANE + (kh - 1) * 48 + (kw - 1)) * 64;
    half8 bf = {};
    if (valid) bf = *reinterpret_cast<const half8*>(xb + delta);
    const unsigned short* wt = wbase + tap * 6144;
#pragma unroll
    for (int mt = 0; mt < 6; ++mt) {
      half8 af = *reinterpret_cast<const half8*>(wt + mt * 512);
      acc[mt] = __builtin_amdgcn_mfma_f32_16x16x32_f16(af, bf, acc[mt], 0, 0, 0);
    }
  }

  // opart[cs][b][ch][colp], ch<81
  const int colp = sp0 + wv * 16 + (lane & 15);
  float* pp = opart + (size_t)(cs * 2 + b) * 81 * SP;
#pragma unroll
  for (int mt = 0; mt < 6; ++mt) {
#pragma unroll
    for (int reg = 0; reg < 4; ++reg) {
      int ch = mt * 16 + (lane >> 4) * 4 + reg;
      if (ch < 81)
        pp[(size_t)ch * SP + colp] = acc[mt][reg];
    }
  }
}

// off[b][ch][p] = cb[ch] + sum_cs opart[cs][b][ch][p]  (float4)
__global__ __launch_bounds__(256) void k_offred(const float* __restrict__ opart,
                                                const float* __restrict__ cb,
                                                float* __restrict__ off) {
  int i = blockIdx.x * 256 + threadIdx.x;  // 2*81*SP/4 = 746,496
  int p4 = i % (SP / 4);
  int ch = (i / (SP / 4)) % 81;
  int b = i / ((SP / 4) * 81);
  size_t base = ((size_t)b * 81 + ch) * SP + p4 * 4;
  float4 s = *reinterpret_cast<const float4*>(&opart[base]);
#pragma unroll
  for (int cs = 1; cs < CS; ++cs) {
    float4 v = *reinterpret_cast<const float4*>(&opart[base + (size_t)cs * 2 * 81 * SP]);
    s.x += v.x; s.y += v.y; s.z += v.z; s.w += v.w;
  }
  float bb = cb[ch];
  s.x += bb; s.y += bb; s.z += bb; s.w += bb;
  *reinterpret_cast<float4*>(&off[base]) = s;
}

// Fused gather + MFMA GEMM (R9 structure: per-lane = channel-chunk gather for
// coalescing). Changes vs R9: (1) all 8 corner loads of a unit issued before
// any blend (one vmcnt drain per unit; launch_bounds(256,4) gives VGPR room);
// (2) scp+vals double-buffered -> 2 barriers per k-step instead of 3.
__global__ __launch_bounds__(256, 4) void k_mainp(const unsigned short* __restrict__ xTh,
                                                  const float* __restrict__ off,
                                                  const unsigned short* __restrict__ wTb,
                                                  float* __restrict__ part) {
  __shared__ __align__(16) unsigned short vals[2][64 * 72]; // [pos][cin] f16
  __shared__ __align__(16) unsigned scp[2][64 * 20];        // [pos][8 x (idx, wgt-h2)]

  const int t = threadIdx.x;
  const int bid = blockIdx.x;                    // kc*576 + j
  const int kc = bid / 576;
  const int j = bid - kc * 576;
  const int tl = (j & 7) * 72 + (j >> 3);        // XCD-contiguous tile blocks
  const int b = tl / NTILE;
  const int tile = tl - b * NTILE;
  const int p0 = tile * 64;

  const char* xb8 = (const char*)(xTh + (size_t)b * SP * 64);
  const float* offb = off + (size_t)b * 81 * SP;

  const int lane = t & 63;
  const int wv = t >> 6;

  // setup-phase constants (pl = lane, cg = wv), hoisted out of the k-loop
  const int pp_ = p0 + lane;
  const int d_ = pp_ / PLANE;
  const int rp_ = pp_ - d_ * PLANE;
  const int h_ = rp_ / 48;
  const int w_ = rp_ - h_ * 48;

  f32x4 acc[4];
#pragma unroll
  for (int mt = 0; mt < 4; ++mt) acc[mt] = f32x4{0.f, 0.f, 0.f, 0.f};

  for (int kk = 0; kk < KPER; ++kk) {
    const int k = kc * KPER + kk;
    const int cur = kk & 1;
    // ---- setup: corners 2wv, 2wv+1 of position p0+lane -> scp[cur]
    {
      int kd = k / 9, kh = (k % 9) / 3, kw2 = k % 3;
      float pd = (float)(d_ + kd - 1) + offb[k * SP + pp_];
      float ph = (float)(h_ + kh - 1) + offb[(27 + k) * SP + pp_];
      float pw = (float)(w_ + kw2 - 1) + offb[(54 + k) * SP + pp_];
      float df = floorf(pd), hf = floorf(ph), wf = floorf(pw);
      float fd = pd - df, fh = ph - hf, fw = pw - wf;
      int d0 = (int)df, h0 = (int)hf, w0i = (int)wf;
#pragma unroll
      for (int cc = 0; cc < 2; ++cc) {
        int c = wv * 2 + cc;
        int cd = c >> 2, ch = (c >> 1) & 1, cwb = c & 1;
        int di = d0 + cd, hi = h0 + ch, wi = w0i + cwb;
        bool v = ((unsigned)di < 8u) && ((unsigned)hi < 48u) && ((unsigned)wi < 48u);
        float wg = (cd ? fd : 1.f - fd) * (ch ? fh : 1.f - fh) * (cwb ? fw : 1.f - fw);
        int dic = min(max(di, 0), 7), hic = min(max(hi, 0), 47), wic = min(max(wi, 0), 47);
        unsigned hs = (unsigned)f2h(v ? wg : 0.f);
        scp[cur][lane * 20 + c * 2] = (unsigned)((dic * 48 + hic) * 48 + wic);
        scp[cur][lane * 20 + c * 2 + 1] = hs | (hs << 16);
      }
    }
    __syncthreads();
    // ---- gather: unit id = u*256+t ; chg = id&7 (8-ch chunk), pos = id>>3.
    // All 8 corner loads issued before any blend (single vmcnt drain).
#pragma unroll
    for (int u = 0; u < 2; ++u) {
      int id = u * 256 + t;
      int chg = id & 7;
      int pl = id >> 3;
      const unsigned* sp = &scp[cur][pl * 20];
      const uint4 m0 = *reinterpret_cast<const uint4*>(sp + 0);
      const uint4 m1 = *reinterpret_cast<const uint4*>(sp + 4);
      const uint4 m2 = *reinterpret_cast<const uint4*>(sp + 8);
      const uint4 m3 = *reinterpret_cast<const uint4*>(sp + 12);
      const int cof = chg << 4;
      uint4 q0 = *reinterpret_cast<const uint4*>(xb8 + (((size_t)m0.x << 7) + cof));
      uint4 q1 = *reinterpret_cast<const uint4*>(xb8 + (((size_t)m0.z << 7) + cof));
      uint4 q2 = *reinterpret_cast<const uint4*>(xb8 + (((size_t)m1.x << 7) + cof));
      uint4 q3 = *reinterpret_cast<const uint4*>(xb8 + (((size_t)m1.z << 7) + cof));
      uint4 q4 = *reinterpret_cast<const uint4*>(xb8 + (((size_t)m2.x << 7) + cof));
      uint4 q5 = *reinterpret_cast<const uint4*>(xb8 + (((size_t)m2.z << 7) + cof));
      uint4 q6 = *reinterpret_cast<const uint4*>(xb8 + (((size_t)m3.x << 7) + cof));
      uint4 q7 = *reinterpret_cast<const uint4*>(xb8 + (((size_t)m3.z << 7) + cof));
      __half2 a2[4];
#pragma unroll
      for (int e = 0; e < 4; ++e) a2[e] = u2h2(0u);
      __half2 w0 = u2h2(m0.y), w1 = u2h2(m0.w), w2 = u2h2(m1.y), w3 = u2h2(m1.w);
      __half2 w4 = u2h2(m2.y), w5 = u2h2(m2.w), w6 = u2h2(m3.y), w7 = u2h2(m3.w);
      a2[0] = __hfma2(u2h2(q0.x), w0, a2[0]); a2[1] = __hfma2(u2h2(q0.y), w0, a2[1]);
      a2[2] = __hfma2(u2h2(q0.z), w0, a2[2]); a2[3] = __hfma2(u2h2(q0.w), w0, a2[3]);
      a2[0] = __hfma2(u2h2(q1.x), w1, a2[0]); a2[1] = __hfma2(u2h2(q1.y), w1, a2[1]);
      a2[2] = __hfma2(u2h2(q1.z), w1, a2[2]); a2[3] = __hfma2(u2h2(q1.w), w1, a2[3]);
      a2[0] = __hfma2(u2h2(q2.x), w2, a2[0]); a2[1] = __hfma2(u2h2(q2.y), w2, a2[1]);
      a2[2] = __hfma2(u2h2(q2.z), w2, a2[2]); a2[3] = __hfma2(u2h2(q2.w), w2, a2[3]);
      a2[0] = __hfma2(u2h2(q3.x), w3, a2[0]); a2[1] = __hfma2(u2h2(q3.y), w3, a2[1]);
      a2[2] = __hfma2(u2h2(q3.z), w3, a2[2]); a2[3] = __hfma2(u2h2(q3.w), w3, a2[3]);
      a2[0] = __hfma2(u2h2(q4.x), w4, a2[0]); a2[1] = __hfma2(u2h2(q4.y), w4, a2[1]);
      a2[2] = __hfma2(u2h2(q4.z), w4, a2[2]); a2[3] = __hfma2(u2h2(q4.w), w4, a2[3]);
      a2[0] = __hfma2(u2h2(q5.x), w5, a2[0]); a2[1] = __hfma2(u2h2(q5.y), w5, a2[1]);
      a2[2] = __hfma2(u2h2(q5.z), w5, a2[2]); a2[3] = __hfma2(u2h2(q5.w), w5, a2[3]);
      a2[0] = __hfma2(u2h2(q6.x), w6, a2[0]); a2[1] = __hfma2(u2h2(q6.y), w6, a2[1]);
      a2[2] = __hfma2(u2h2(q6.z), w6, a2[2]); a2[3] = __hfma2(u2h2(q6.w), w6, a2[3]);
      a2[0] = __hfma2(u2h2(q7.x), w7, a2[0]); a2[1] = __hfma2(u2h2(q7.y), w7, a2[1]);
      a2[2] = __hfma2(u2h2(q7.z), w7, a2[2]); a2[3] = __hfma2(u2h2(q7.w), w7, a2[3]);
      *reinterpret_cast<uint4*>(&vals[cur][pl * 72 + chg * 8]) =
          uint4{h22u(a2[0]), h22u(a2[1]), h22u(a2[2]), h22u(a2[3])};
    }
    __syncthreads();
    // ---- MFMA: C[co][pos] += W[co][cin] * V[cin][pos]; A from L2, B from LDS
    {
      const unsigned short* wk = wTb + (size_t)k * 4096;
#pragma unroll
      for (int s = 0; s < 2; ++s) {
        half8 bfr = *reinterpret_cast<const half8*>(
            &vals[cur][(wv * 16 + (lane & 15)) * 72 + s * 32 + (lane >> 4) * 8]);
#pragma unroll
        for (int mt = 0; mt < 4; ++mt) {
          half8 afr = *reinterpret_cast<const half8*>(
              wk + mt * 1024 + s * 512 + (lane & 15) * 32 + (lane >> 4) * 8);
          acc[mt] = __builtin_amdgcn_mfma_f32_16x16x32_f16(afr, bfr, acc[mt], 0, 0, 0);
        }
      }
    }
    // no end-of-loop barrier: next iteration uses buffer cur^1
  }

  // part[kc][b][tile][co][pos]; co = mt*16+(lane>>4)*4+reg, pos = wv*16+(lane&15)
  float* pp = part + ((size_t)(kc * 2 + b) * NTILE + tile) * 4096;
#pragma unroll
  for (int mt = 0; mt < 4; ++mt) {
#pragma unroll
    for (int reg = 0; reg < 4; ++reg) {
      int co = mt * 16 + (lane >> 4) * 4 + reg;
      pp[co * 64 + wv * 16 + (lane & 15)] = acc[mt][reg];
    }
  }
}

// out[b][co][p] = bias[co] + sum_kc part[kc][b][tile][co][pos]  (float4)
__global__ __launch_bounds__(256) void k_red(const float* __restrict__ part,
                                             const float* __restrict__ bias,
                                             float* __restrict__ out) {
  int i = blockIdx.x * 256 + threadIdx.x;  // 589,824 float4 units
  int p4 = i % (SP / 4);
  int co = (i / (SP / 4)) & 63;
  int b = i / ((SP / 4) * 64);
  int p = p4 * 4;
  int tile = p >> 6, pos = p & 63;
  size_t base = ((size_t)b * NTILE + tile) * 4096 + co * 64 + pos;
  float4 s = *reinterpret_cast<const float4*>(&part[base]);
#pragma unroll
  for (int kc = 1; kc < KC; ++kc) {
    float4 v = *reinterpret_cast<const float4*>(&part[base + (size_t)kc * (2 * NTILE * 4096)]);
    s.x += v.x; s.y += v.y; s.z += v.z; s.w += v.w;
  }
  float bb = bias[co];
  s.x += bb; s.y += bb; s.z += bb; s.w += bb;
  *reinterpret_cast<float4*>(&out[((size_t)(b * 64 + co)) * SP + p]) = s;
}

extern "C" void kernel_launch(void* const* d_in, const int* in_sizes, int n_in,
                              void* d_out, int out_size, void* d_ws, size_t ws_size,
                              hipStream_t stream) {
  const float* x = (const float*)d_in[0];
  const float* cw = (const float*)d_in[1];
  const float* cb = (const float*)d_in[2];
  const float* w = (const float*)d_in[3];
  const float* bias = (const float*)d_in[4];
  float* out = (float*)d_out;

  char* ws = (char*)d_ws;
  float* off = (float*)ws;                                   // 11,943,936 B
  unsigned short* xTh = (unsigned short*)(ws + 11943936);    //  4,718,592 B
  unsigned short* wTb = (unsigned short*)(ws + 16662528);    //    221,184 B
  unsigned short* wq = (unsigned short*)(ws + 16883712);     //    331,776 B
  float* part = (float*)(ws + 17215488);                     // KC*9,437,184 = 28,311,552 B
  float* opart = (float*)(ws + 45527040);                    // CS*11,943,936 = 23,887,872 B

  hipLaunchKernelGGL(k_xTh, dim3(9216), dim3(256), 0, stream, x, xTh);
  hipLaunchKernelGGL(k_wTb, dim3(432), dim3(256), 0, stream, w, wTb);
  hipLaunchKernelGGL(k_offwq, dim3(648), dim3(256), 0, stream, cw, wq);
  hipLaunchKernelGGL(k_offm3, dim3(CS * 576), dim3(256), 0, stream, xTh, wq, opart);
  hipLaunchKernelGGL(k_offred, dim3(2916), dim3(256), 0, stream, opart, cb, off);
  hipLaunchKernelGGL(k_mainp, dim3(KC * 576), dim3(256), 0, stream, xTh, off, wTb, part);
  hipLaunchKernelGGL(k_red, dim3(2304), dim3(256), 0, stream, part, bias, out);
}

// Round 12
// 162.192 us; speedup vs baseline: 1.4261x; 1.0021x over previous
//
#include <hip/hip_runtime.h>
#include <hip/hip_fp16.h>

namespace {
constexpr int Bn = 2, Cin = 64, Cout = 64;
constexpr int Dd = 8, Hh = 48, Wd = 48;
constexpr int K = 27;
constexpr int SP = Dd * Hh * Wd;   // 18432
constexpr int PLANE = Hh * Wd;     // 2304
constexpr int NTILE = SP / 64;     // 288 position tiles per batch
constexpr int KC = 3;              // K-split factor (main GEMM); KPER = 9
constexpr int KPER = K / KC;
constexpr int CS = 2;              // cin-split factor (offset conv)
}

typedef __attribute__((ext_vector_type(8))) _Float16 half8;
typedef __attribute__((ext_vector_type(4))) float f32x4;

__device__ __forceinline__ unsigned short f2h(float f) {  // RNE float->f16 bits
  return __half_as_ushort(__float2half(f));
}
__device__ __forceinline__ __half2 u2h2(unsigned u) {
  return __builtin_bit_cast(__half2, u);
}
__device__ __forceinline__ unsigned h22u(__half2 h) {
  return __builtin_bit_cast(unsigned, h);
}

// x [B,C,D,H,W] -> xTh [B, spatial, C] f16 (channels-last)
__global__ __launch_bounds__(256) void k_xTh(const float* __restrict__ x,
                                             unsigned short* __restrict__ xTh) {
  int i = blockIdx.x * 256 + threadIdx.x;   // B*SP*Cin = 2,359,296
  int c = i & 63;
  int rest = i >> 6;
  int p = rest % SP;
  int b = rest / SP;
  xTh[i] = f2h(x[(b * Cin + c) * SP + p]);
}

// main weights -> per-lane-contiguous MFMA A-frag layout, f16:
// wTb[k][mt(4)][s(2)][row(16)][kg(4)][j(8)] ; co = mt*16+row, cin = s*32+kg*8+j
__global__ __launch_bounds__(256) void k_wTb(const float* __restrict__ w,
                                             unsigned short* __restrict__ wTb) {
  int i = blockIdx.x * 256 + threadIdx.x;   // 27*4096 = 110,592
  int j = i & 7, kg = (i >> 3) & 3, row = (i >> 5) & 15;
  int s = (i >> 9) & 1, mt = (i >> 10) & 3, k = i >> 12;
  int co = mt * 16 + row, cin = s * 32 + kg * 8 + j;
  wTb[i] = f2h(w[((size_t)co * Cin + cin) * K + k]);
}

// offset-conv weights -> A-frag layout keyed by (tap, cin-half):
// wq[tap][cs(2)][mt(6)][row(16)][kg(4)][j(8)] ; ch = mt*16+row (pad >=81 -> 0),
// cin = cs*32+kg*8+j
__global__ __launch_bounds__(256) void k_offwq(const float* __restrict__ cw,
                                               unsigned short* __restrict__ wq) {
  int i = blockIdx.x * 256 + threadIdx.x;   // 27*2*6*512 = 165,888
  int j = i & 7, kg = (i >> 3) & 3, row = (i >> 5) & 15;
  int rest = i >> 9;          // 0..323
  int mt = rest % 6;
  int rest2 = rest / 6;       // 0..53
  int cs = rest2 & 1;
  int tap = rest2 >> 1;
  int ch = mt * 16 + row, cin = cs * 32 + kg * 8 + j;
  float v = (ch < 81) ? cw[((size_t)ch * 64 + cin) * 27 + tap] : 0.f;
  wq[i] = f2h(v);
}

// Offset conv, barrier-free MFMA (validated round 9). No LDS.
__global__ __launch_bounds__(256) void k_offm3(const unsigned short* __restrict__ xTh,
                                               const unsigned short* __restrict__ wq,
                                               float* __restrict__ opart) {
  const int t = threadIdx.x;
  const int lane = t & 63;
  const int wv = t >> 6;
  const int bid = blockIdx.x;              // cs*576 + nb ; 1152 total
  const int cs = bid / 576;
  const int nb = bid - cs * 576;
  const int n0 = nb * 64;
  const int b = n0 / SP;
  const int sp0 = n0 - b * SP;

  const int q = sp0 + wv * 16 + (lane & 15);   // this lane's output position
  const int d = q / PLANE;
  const int rp = q - d * PLANE;
  const int h = rp / 48;
  const int w = rp - h * 48;

  const unsigned short* xb =
      xTh + ((size_t)b * SP + q) * 64 + cs * 32 + (lane >> 4) * 8;
  const unsigned short* wbase =
      wq + cs * 3072 + (lane & 15) * 32 + (lane >> 4) * 8;

  f32x4 acc[6];
#pragma unroll
  for (int mt = 0; mt < 6; ++mt) acc[mt] = f32x4{0.f, 0.f, 0.f, 0.f};

#pragma unroll
  for (int tap = 0; tap < 27; ++tap) {
    const int kd = tap / 9, kh = (tap % 9) / 3, kw = tap % 3;
    const int dd = d + kd - 1, hh = h + kh - 1, ww = w + kw - 1;
    const bool valid = ((unsigned)dd < 8u) & ((unsigned)hh < 48u) & ((unsigned)ww < 48u);
    const int delta = ((kd - 1) * PLANE + (kh - 1) * 48 + (kw - 1)) * 64;
    half8 bf = {};
    if (valid) bf = *reinterpret_cast<const half8*>(xb + delta);
    const unsigned short* wt = wbase + tap * 6144;
#pragma unroll
    for (int mt = 0; mt < 6; ++mt) {
      half8 af = *reinterpret_cast<const half8*>(wt + mt * 512);
      acc[mt] = __builtin_amdgcn_mfma_f32_16x16x32_f16(af, bf, acc[mt], 0, 0, 0);
    }
  }

  // opart[cs][b][ch][colp], ch<81
  const int colp = sp0 + wv * 16 + (lane & 15);
  float* pp = opart + (size_t)(cs * 2 + b) * 81 * SP;
#pragma unroll
  for (int mt = 0; mt < 6; ++mt) {
#pragma unroll
    for (int reg = 0; reg < 4; ++reg) {
      int ch = mt * 16 + (lane >> 4) * 4 + reg;
      if (ch < 81)
        pp[(size_t)ch * SP + colp] = acc[mt][reg];
    }
  }
}

// off[b][ch][p] = cb[ch] + sum_cs opart[cs][b][ch][p]  (float4)
__global__ __launch_bounds__(256) void k_offred(const float* __restrict__ opart,
                                                const float* __restrict__ cb,
                                                float* __restrict__ off) {
  int i = blockIdx.x * 256 + threadIdx.x;  // 2*81*SP/4 = 746,496
  int p4 = i % (SP / 4);
  int ch = (i / (SP / 4)) % 81;
  int b = i / ((SP / 4) * 81);
  size_t base = ((size_t)b * 81 + ch) * SP + p4 * 4;
  float4 s = *reinterpret_cast<const float4*>(&opart[base]);
#pragma unroll
  for (int cs = 1; cs < CS; ++cs) {
    float4 v = *reinterpret_cast<const float4*>(&opart[base + (size_t)cs * 2 * 81 * SP]);
    s.x += v.x; s.y += v.y; s.z += v.z; s.w += v.w;
  }
  float bb = cb[ch];
  s.x += bb; s.y += bb; s.z += bb; s.w += bb;
  *reinterpret_cast<float4*>(&off[base]) = s;
}

// Fused gather + MFMA GEMM, wave-self-sufficient: wave wv owns positions
// wv*16..wv*16+15 for setup, gather AND MFMA B-operand -> zero __syncthreads.
// Gather keeps R9's coalescing: lanes (pl=lane>>3, chg=lane&7) -> 8 lanes load
// one corner's contiguous 128B. scp reads: 8-way broadcast, distinct banks.
__global__ __launch_bounds__(256, 4) void k_mainp(const unsigned short* __restrict__ xTh,
                                                  const float* __restrict__ off,
                                                  const unsigned short* __restrict__ wTb,
                                                  float* __restrict__ part) {
  __shared__ __align__(16) unsigned scp[4][16 * 20];         // per-wave [pos16][20w]
  __shared__ __align__(16) unsigned short vals[4][16 * 72];  // per-wave [pos16][cin]

  const int t = threadIdx.x;
  const int lane = t & 63;
  const int wv = t >> 6;
  const int bid = blockIdx.x;                    // kc*576 + j
  const int kc = bid / 576;
  const int j = bid - kc * 576;
  const int tl = (j & 7) * 72 + (j >> 3);        // XCD-contiguous tile blocks
  const int b = tl / NTILE;
  const int tile = tl - b * NTILE;
  const int p0 = tile * 64;

  const char* xb8 = (const char*)(xTh + (size_t)b * SP * 64);
  const float* offb = off + (size_t)b * 81 * SP;

  const int posl = lane & 15;
  const int quad = lane >> 4;
  // setup: this lane computes corners 2*quad, 2*quad+1 of position p
  const int p = p0 + wv * 16 + posl;
  const int d_ = p / PLANE;
  const int rp_ = p - d_ * PLANE;
  const int h_ = rp_ / 48;
  const int w_ = rp_ - h_ * 48;
  const int kd = kc;                              // KPER==9 -> k/9 == kc
  unsigned* myrow = &scp[wv][posl * 20];

  // gather: this lane handles chunk gchg of rows gpl0 (u=0) and gpl0+8 (u=1)
  const int gpl0 = lane >> 3;   // 0..7
  const int gchg = lane & 7;

  f32x4 acc[4];
#pragma unroll
  for (int mt = 0; mt < 4; ++mt) acc[mt] = f32x4{0.f, 0.f, 0.f, 0.f};

  for (int kk = 0; kk < KPER; ++kk) {
    const int k = kc * KPER + kk;
    const int kh = kk / 3, kw2 = kk % 3;
    // ---- setup -> per-wave scp (same-wave LDS ordering; no block barrier)
    {
      float pd = (float)(d_ + kd - 1) + offb[k * SP + p];
      float ph = (float)(h_ + kh - 1) + offb[(27 + k) * SP + p];
      float pw = (float)(w_ + kw2 - 1) + offb[(54 + k) * SP + p];
      float df = floorf(pd), hf = floorf(ph), wf = floorf(pw);
      float fd = pd - df, fh = ph - hf, fw = pw - wf;
      int d0 = (int)df, h0 = (int)hf, w0i = (int)wf;
      unsigned pk[4];
#pragma unroll
      for (int cc = 0; cc < 2; ++cc) {
        int c = quad * 2 + cc;
        int cd = c >> 2, ch = (c >> 1) & 1, cwb = c & 1;
        int di = d0 + cd, hi = h0 + ch, wi = w0i + cwb;
        bool v = ((unsigned)di < 8u) && ((unsigned)hi < 48u) && ((unsigned)wi < 48u);
        float wg = (cd ? fd : 1.f - fd) * (ch ? fh : 1.f - fh) * (cwb ? fw : 1.f - fw);
        int dic = min(max(di, 0), 7), hic = min(max(hi, 0), 47), wic = min(max(wi, 0), 47);
        unsigned hs = (unsigned)f2h(v ? wg : 0.f);
        pk[cc * 2] = (unsigned)((dic * 48 + hic) * 48 + wic);
        pk[cc * 2 + 1] = hs | (hs << 16);
      }
      *reinterpret_cast<uint4*>(myrow + quad * 4) = uint4{pk[0], pk[1], pk[2], pk[3]};
    }
    // ---- gather: 2 units/lane, rows gpl0 and gpl0+8 of this wave's region
#pragma unroll
    for (int u = 0; u < 2; ++u) {
      const int pl = gpl0 + u * 8;
      const unsigned* sp = &scp[wv][pl * 20];
      const uint4 m0 = *reinterpret_cast<const uint4*>(sp + 0);
      const uint4 m1 = *reinterpret_cast<const uint4*>(sp + 4);
      const uint4 m2 = *reinterpret_cast<const uint4*>(sp + 8);
      const uint4 m3 = *reinterpret_cast<const uint4*>(sp + 12);
      const int cof = gchg << 4;
      uint4 q0 = *reinterpret_cast<const uint4*>(xb8 + (((size_t)m0.x << 7) + cof));
      uint4 q1 = *reinterpret_cast<const uint4*>(xb8 + (((size_t)m0.z << 7) + cof));
      uint4 q2 = *reinterpret_cast<const uint4*>(xb8 + (((size_t)m1.x << 7) + cof));
      uint4 q3 = *reinterpret_cast<const uint4*>(xb8 + (((size_t)m1.z << 7) + cof));
      uint4 q4 = *reinterpret_cast<const uint4*>(xb8 + (((size_t)m2.x << 7) + cof));
      uint4 q5 = *reinterpret_cast<const uint4*>(xb8 + (((size_t)m2.z << 7) + cof));
      uint4 q6 = *reinterpret_cast<const uint4*>(xb8 + (((size_t)m3.x << 7) + cof));
      uint4 q7 = *reinterpret_cast<const uint4*>(xb8 + (((size_t)m3.z << 7) + cof));
      __half2 a2[4];
#pragma unroll
      for (int e = 0; e < 4; ++e) a2[e] = u2h2(0u);
      __half2 w0 = u2h2(m0.y), w1 = u2h2(m0.w), w2 = u2h2(m1.y), w3 = u2h2(m1.w);
      __half2 w4 = u2h2(m2.y), w5 = u2h2(m2.w), w6 = u2h2(m3.y), w7 = u2h2(m3.w);
      a2[0] = __hfma2(u2h2(q0.x), w0, a2[0]); a2[1] = __hfma2(u2h2(q0.y), w0, a2[1]);
      a2[2] = __hfma2(u2h2(q0.z), w0, a2[2]); a2[3] = __hfma2(u2h2(q0.w), w0, a2[3]);
      a2[0] = __hfma2(u2h2(q1.x), w1, a2[0]); a2[1] = __hfma2(u2h2(q1.y), w1, a2[1]);
      a2[2] = __hfma2(u2h2(q1.z), w1, a2[2]); a2[3] = __hfma2(u2h2(q1.w), w1, a2[3]);
      a2[0] = __hfma2(u2h2(q2.x), w2, a2[0]); a2[1] = __hfma2(u2h2(q2.y), w2, a2[1]);
      a2[2] = __hfma2(u2h2(q2.z), w2, a2[2]); a2[3] = __hfma2(u2h2(q2.w), w2, a2[3]);
      a2[0] = __hfma2(u2h2(q3.x), w3, a2[0]); a2[1] = __hfma2(u2h2(q3.y), w3, a2[1]);
      a2[2] = __hfma2(u2h2(q3.z), w3, a2[2]); a2[3] = __hfma2(u2h2(q3.w), w3, a2[3]);
      a2[0] = __hfma2(u2h2(q4.x), w4, a2[0]); a2[1] = __hfma2(u2h2(q4.y), w4, a2[1]);
      a2[2] = __hfma2(u2h2(q4.z), w4, a2[2]); a2[3] = __hfma2(u2h2(q4.w), w4, a2[3]);
      a2[0] = __hfma2(u2h2(q5.x), w5, a2[0]); a2[1] = __hfma2(u2h2(q5.y), w5, a2[1]);
      a2[2] = __hfma2(u2h2(q5.z), w5, a2[2]); a2[3] = __hfma2(u2h2(q5.w), w5, a2[3]);
      a2[0] = __hfma2(u2h2(q6.x), w6, a2[0]); a2[1] = __hfma2(u2h2(q6.y), w6, a2[1]);
      a2[2] = __hfma2(u2h2(q6.z), w6, a2[2]); a2[3] = __hfma2(u2h2(q6.w), w6, a2[3]);
      a2[0] = __hfma2(u2h2(q7.x), w7, a2[0]); a2[1] = __hfma2(u2h2(q7.y), w7, a2[1]);
      a2[2] = __hfma2(u2h2(q7.z), w7, a2[2]); a2[3] = __hfma2(u2h2(q7.w), w7, a2[3]);
      *reinterpret_cast<uint4*>(&vals[wv][pl * 72 + gchg * 8]) =
          uint4{h22u(a2[0]), h22u(a2[1]), h22u(a2[2]), h22u(a2[3])};
    }
    // ---- MFMA: B-frag read from this wave's own vals region (same-wave order)
    {
      const unsigned short* wk = wTb + (size_t)k * 4096;
#pragma unroll
      for (int s = 0; s < 2; ++s) {
        half8 bfr = *reinterpret_cast<const half8*>(
            &vals[wv][posl * 72 + s * 32 + quad * 8]);
#pragma unroll
        for (int mt = 0; mt < 4; ++mt) {
          half8 afr = *reinterpret_cast<const half8*>(
              wk + mt * 1024 + s * 512 + posl * 32 + quad * 8);
          acc[mt] = __builtin_amdgcn_mfma_f32_16x16x32_f16(afr, bfr, acc[mt], 0, 0, 0);
        }
      }
    }
  }

  // part[kc][b][tile][co][pos]; co = mt*16+quad*4+reg, pos = wv*16+posl
  float* pp = part + ((size_t)(kc * 2 + b) * NTILE + tile) * 4096;
#pragma unroll
  for (int mt = 0; mt < 4; ++mt) {
#pragma unroll
    for (int reg = 0; reg < 4; ++reg) {
      int co = mt * 16 + quad * 4 + reg;
      pp[co * 64 + wv * 16 + posl] = acc[mt][reg];
    }
  }
}

// out[b][co][p] = bias[co] + sum_kc part[kc][b][tile][co][pos]  (float4)
__global__ __launch_bounds__(256) void k_red(const float* __restrict__ part,
                                             const float* __restrict__ bias,
                                             float* __restrict__ out) {
  int i = blockIdx.x * 256 + threadIdx.x;  // 589,824 float4 units
  int p4 = i % (SP / 4);
  int co = (i / (SP / 4)) & 63;
  int b = i / ((SP / 4) * 64);
  int p = p4 * 4;
  int tile = p >> 6, pos = p & 63;
  size_t base = ((size_t)b * NTILE + tile) * 4096 + co * 64 + pos;
  float4 s = *reinterpret_cast<const float4*>(&part[base]);
#pragma unroll
  for (int kc = 1; kc < KC; ++kc) {
    float4 v = *reinterpret_cast<const float4*>(&part[base + (size_t)kc * (2 * NTILE * 4096)]);
    s.x += v.x; s.y += v.y; s.z += v.z; s.w += v.w;
  }
  float bb = bias[co];
  s.x += bb; s.y += bb; s.z += bb; s.w += bb;
  *reinterpret_cast<float4*>(&out[((size_t)(b * 64 + co)) * SP + p]) = s;
}

extern "C" void kernel_launch(void* const* d_in, const int* in_sizes, int n_in,
                              void* d_out, int out_size, void* d_ws, size_t ws_size,
                              hipStream_t stream) {
  const float* x = (const float*)d_in[0];
  const float* cw = (const float*)d_in[1];
  const float* cb = (const float*)d_in[2];
  const float* w = (const float*)d_in[3];
  const float* bias = (const float*)d_in[4];
  float* out = (float*)d_out;

  char* ws = (char*)d_ws;
  float* off = (float*)ws;                                   // 11,943,936 B
  unsigned short* xTh = (unsigned short*)(ws + 11943936);    //  4,718,592 B
  unsigned short* wTb = (unsigned short*)(ws + 16662528);    //    221,184 B
  unsigned short* wq = (unsigned short*)(ws + 16883712);     //    331,776 B
  float* part = (float*)(ws + 17215488);                     // KC*9,437,184 = 28,311,552 B
  float* opart = (float*)(ws + 45527040);                    // CS*11,943,936 = 23,887,872 B

  hipLaunchKernelGGL(k_xTh, dim3(9216), dim3(256), 0, stream, x, xTh);
  hipLaunchKernelGGL(k_wTb, dim3(432), dim3(256), 0, stream, w, wTb);
  hipLaunchKernelGGL(k_offwq, dim3(648), dim3(256), 0, stream, cw, wq);
  hipLaunchKernelGGL(k_offm3, dim3(CS * 576), dim3(256), 0, stream, xTh, wq, opart);
  hipLaunchKernelGGL(k_offred, dim3(2916), dim3(256), 0, stream, opart, cb, off);
  hipLaunchKernelGGL(k_mainp, dim3(KC * 576), dim3(256), 0, stream, xTh, off, wTb, part);
  hipLaunchKernelGGL(k_red, dim3(2304), dim3(256), 0, stream, part, bias, out);
}